// Round 14
// baseline (54.265 us; speedup 1.0000x reference)
//
#include <hip/hip_runtime.h>
#include <math.h>

#define NQ 14
#define NSTATE (1 << 14)
#define DEPTH  6
#define NT     1024             // 16 waves/block

// dword-index swizzle: XOR bits 6,7,8 into 2,3,4 (GF(2)-linear)
__device__ __forceinline__ int swz(int n) { return n ^ ((n >> 4) & 28); }

// fused CNOT ladders (even after odd): m = sigma_e(sigma_o(n))
__device__ __forceinline__ int sigma(int n) {
    int m = n ^ ((n & 0x1554) >> 1);
    return m ^ ((m & 0x2AAA) >> 1);
}

// RY on p-index bit JB over a 16-amp real register block
template <int JB>
__device__ __forceinline__ void ry16(float (&p)[16], float c, float s) {
#pragma unroll
    for (int i = 0; i < 16; ++i) {
        if (!((i >> JB) & 1)) {
            const int i1 = i | (1 << JB);
            float a0 = p[i], a1 = p[i1];
            p[i]  = c * a0 - s * a1;
            p[i1] = s * a0 + c * a1;
        }
    }
}

// RY across lane bit 0/1 via DPP quad_perm (VALU pipe, verified r9/r10).
// CTRL: 0xB1 = xor lane^1, 0x4E = xor lane^2.  sg = (lane bit set)? +s : -s
template <int CTRL>
__device__ __forceinline__ void ry_dpp(float (&p)[16], float c, float sg) {
#pragma unroll
    for (int i = 0; i < 16; ++i) {
        float partner = __int_as_float(__builtin_amdgcn_update_dpp(
            0, __float_as_int(p[i]), CTRL, 0xF, 0xF, true));
        p[i] = c * p[i] + sg * partner;
    }
}

__global__ __launch_bounds__(NT, 4)
void vqc_kernel(const float* __restrict__ X,    // (512,14)
                const float* __restrict__ TH,   // (6,14)
                const float* __restrict__ A,    // (14,28)
                const float* __restrict__ Bc,   // (14,28)  unused: state stays real
                const float* __restrict__ D,    // (14,8)
                float* __restrict__ out)        // (512,2)
{
    __shared__ __align__(16) float st[NSTATE];  // 64 KiB real state
    __shared__ float2 tb[DEPTH * NQ];           // (cos,sin) per theta
    __shared__ float2 xf[NQ];                   // (c-s, c+s) per amplitude bit j
    __shared__ float  red[2 * (NT / 64)];

    const int t = threadIdx.x;
    const int b = blockIdx.x;

    // ---- trig tables (uniform work once per block) ----
    if (t < DEPTH * NQ) {
        float s, c;
        __sincosf(0.5f * TH[t], &s, &c);
        tb[t] = make_float2(c, s);
    } else if (t < DEPTH * NQ + NQ) {
        const int j = t - DEPTH * NQ;           // amplitude-bit j <-> wire 13-j
        float s, c;
        __sincosf(0.5f * X[b * NQ + (13 - j)], &s, &c);
        xf[j] = make_float2(c - s, c + s);
    }
    __syncthreads();

    // ---- layer 0 P1: product state at sigma(n), rotate wires 13..10 (amp 0-3) ----
    {
        const int mt = sigma(t << 4);
        float sh = 1.0f / 128.0f;
#pragma unroll
        for (int j = 4; j < 14; ++j) {
            float2 f = xf[j];
            sh *= ((mt >> j) & 1) ? f.y : f.x;
        }
        float fa[4], fb[4];
#pragma unroll
        for (int j = 0; j < 4; ++j) {
            float2 f = xf[j];
            const int mj = (mt >> j) & 1;
            fa[j] = mj ? f.y : f.x;
            fb[j] = mj ? f.x : f.y;
        }
        float p[16];
#pragma unroll
        for (int i = 0; i < 16; ++i) {
            const int sl = sigma(i);
            float v = sh;
            v *= (sl & 1)        ? fb[0] : fa[0];
            v *= ((sl >> 1) & 1) ? fb[1] : fa[1];
            v *= ((sl >> 2) & 1) ? fb[2] : fa[2];
            v *= ((sl >> 3) & 1) ? fb[3] : fa[3];
            p[i] = v;
        }
        float2 q0 = tb[13], q1 = tb[12], q2 = tb[11], q3 = tb[10];
        ry16<0>(p, q0.x, q0.y);
        ry16<1>(p, q1.x, q1.y);
        ry16<2>(p, q2.x, q2.y);
        ry16<3>(p, q3.x, q3.y);
        const int wb = swz(t << 4);
#pragma unroll
        for (int g = 0; g < 4; ++g)
            *(float4*)&st[wb ^ (g << 2)] =
                make_float4(p[4 * g], p[4 * g + 1], p[4 * g + 2], p[4 * g + 3]);
    }
    __syncthreads();

    // ---- layers: P1 (CNOT + 13-10), P2 (9-6 reg + 5,4 DPP), P3 (3-0) ----
    for (int k = 0; k < DEPTH; ++k) {
        const float2* tbk = tb + k * NQ;

        if (k > 0) {
            // P1: gather through sigma (b128). Lane-dependent XOR 12 folded
            // into the read address; remaining permute = compile-time renaming.
            const int rb = swz(sigma(t << 4) & ~15) ^ ((t & 1) * 12);
            float tmpf[16];
#pragma unroll
            for (int g = 0; g < 4; ++g)
                *(float4*)&tmpf[g * 4] = *(const float4*)&st[rb ^ (g << 2)];
            float p[16];
#pragma unroll
            for (int i = 0; i < 16; ++i) {
                const int i0 = i & 1, i1 = (i >> 1) & 1, i2 = (i >> 2) & 1, i3 = (i >> 3) & 1;
                const int s = (i0 ^ i1 ^ i2) | ((i1 ^ i2) << 1) | ((i2 ^ i3) << 2) | (i3 << 3);
                p[i] = tmpf[s];                  // compile-time shuffle
            }
            __syncthreads();                     // all gather-reads before any write
            float2 q0 = tbk[13], q1 = tbk[12], q2 = tbk[11], q3 = tbk[10];
            ry16<0>(p, q0.x, q0.y);
            ry16<1>(p, q1.x, q1.y);
            ry16<2>(p, q2.x, q2.y);
            ry16<3>(p, q3.x, q3.y);
            const int wb = swz(t << 4);
#pragma unroll
            for (int g = 0; g < 4; ++g)
                *(float4*)&st[wb ^ (g << 2)] =
                    make_float4(p[4 * g], p[4 * g + 1], p[4 * g + 2], p[4 * g + 3]);
            __syncthreads();
        }

        // P2: in-place RMW. regs = amp 4-7 (wires 9-6); DPP lanes t0,t1 = amp 8,9
        // (wires 5,4). Pairs over amp bit 5 -> additive +32 dwords (ds_read2).
        {
            const int raw = ((t >> 2) & 15) | ((t & 1) << 8) | ((t & 2) << 8)
                          | (((t >> 6) & 15) << 10);
            const int base2 = swz(raw);
            float p[16];
#pragma unroll
            for (int ip = 0; ip < 16; ++ip) {
                if ((ip & 2) == 0) {
                    const int v = base2 ^ (ip << 4) ^ (ip & 12);   // swz(ip<<4) folded
                    p[ip]     = st[v];
                    p[ip | 2] = st[v + 32];
                }
            }
            float2 q0 = tbk[9], q1 = tbk[8], q2 = tbk[7], q3 = tbk[6];
            ry16<0>(p, q0.x, q0.y);             // amp4 <-> wire 9
            ry16<1>(p, q1.x, q1.y);             // amp5 <-> wire 8
            ry16<2>(p, q2.x, q2.y);             // amp6 <-> wire 7
            ry16<3>(p, q3.x, q3.y);             // amp7 <-> wire 6
            float2 w5 = tbk[5], w4 = tbk[4];
            const float sg5 = (t & 1) ? w5.y : -w5.y;   // amp8 = lane bit 0
            const float sg4 = (t & 2) ? w4.y : -w4.y;   // amp9 = lane bit 1
            ry_dpp<0xB1>(p, w5.x, sg5);
            ry_dpp<0x4E>(p, w4.x, sg4);
#pragma unroll
            for (int ip = 0; ip < 16; ++ip) {
                if ((ip & 2) == 0) {
                    const int v = base2 ^ (ip << 4) ^ (ip & 12);
                    st[v]      = p[ip];
                    st[v + 32] = p[ip | 2];
                }
            }
            __syncthreads();
        }

        // P3: regs = amp 10-13 (wires 3-0), purely additive addresses.
        // Last layer: no store — expectations fused, SGPR-coefficient style.
        {
            const int base3 = swz(t);
            float p[16];
#pragma unroll
            for (int i = 0; i < 16; ++i) p[i] = st[base3 + (i << 10)];
            float2 q0 = tbk[3], q1 = tbk[2], q2 = tbk[1], q3 = tbk[0];
            ry16<0>(p, q0.x, q0.y);             // amp10 <-> wire 3
            ry16<1>(p, q1.x, q1.y);             // amp11 <-> wire 2
            ry16<2>(p, q2.x, q2.y);             // amp12 <-> wire 1
            ry16<3>(p, q3.x, q3.y);             // amp13 <-> wire 0
            if (k < DEPTH - 1) {
#pragma unroll
                for (int i = 0; i < 16; ++i) st[base3 + (i << 10)] = p[i];
                __syncthreads();
            } else {
                // ---- fused expectations; coefficients stay in SGPRs ----
                // e = 2*(sum_i D[i+1] psi_i^2 + sum_{i>j} A[kk] psi_i psi_j)
                float acc0 = 0.0f, acc1 = 0.0f;
                // q=0: obs index i = p bits {1,2,3} (amps 11,12,13); group = p bit 0
#pragma unroll
                for (int a = 0; a < 2; ++a) {
#pragma unroll
                    for (int r = 0; r < 7; ++r) {
                        float v = p[((r + 1) << 1) | a] ;  // psi_{r+1}... careful below
                    }
                }
                // explicit, index-verified accumulation:
#pragma unroll
                for (int a = 0; a < 2; ++a) {
#pragma unroll
                    for (int i = 0; i < 7; ++i) {          // diag D[0*8 + i+1] * psi_i^2
                        float v = p[(i << 1) | a];
                        acc0 = fmaf(v * v, D[i + 1], acc0);
                    }
                    int kk = 0;
#pragma unroll
                    for (int i = 1; i < 8; ++i)
#pragma unroll
                        for (int j = 0; j < i; ++j, ++kk) { // cross A[0*28 + kk]
                            float pr = p[(i << 1) | a] * p[(j << 1) | a];
                            acc0 = fmaf(pr, A[kk], acc0);
                        }
                }
                // q=1: obs index i = p bits {0,1,2} (amps 10,11,12); group = p bit 3
#pragma unroll
                for (int bb = 0; bb < 2; ++bb) {
#pragma unroll
                    for (int i = 0; i < 7; ++i) {
                        float v = p[i | (bb << 3)];
                        acc1 = fmaf(v * v, D[8 + i + 1], acc1);
                    }
                    int kk = 0;
#pragma unroll
                    for (int i = 1; i < 8; ++i)
#pragma unroll
                        for (int j = 0; j < i; ++j, ++kk) {
                            float pr = p[i | (bb << 3)] * p[j | (bb << 3)];
                            acc1 = fmaf(pr, A[28 + kk], acc1);
                        }
                }
                float e0 = acc0 + acc0;
                float e1 = acc1 + acc1;
                // ---- block reduction ----
#pragma unroll
                for (int o = 32; o > 0; o >>= 1) {
                    e0 += __shfl_down(e0, o);
                    e1 += __shfl_down(e1, o);
                }
                if ((t & 63) == 0) {
                    red[(t >> 6) * 2]     = e0;
                    red[(t >> 6) * 2 + 1] = e1;
                }
                __syncthreads();
                if (t == 0) {
                    float s0 = 0.0f, s1 = 0.0f;
#pragma unroll
                    for (int i = 0; i < NT / 64; ++i) {
                        s0 += red[i * 2];
                        s1 += red[i * 2 + 1];
                    }
                    out[b * 2 + 0] = s0;
                    out[b * 2 + 1] = s1;
                }
            }
        }
    }
}

extern "C" void kernel_launch(void* const* d_in, const int* in_sizes, int n_in,
                              void* d_out, int out_size, void* d_ws, size_t ws_size,
                              hipStream_t stream) {
    const float* X  = (const float*)d_in[0];
    const float* TH = (const float*)d_in[1];
    const float* A  = (const float*)d_in[2];
    const float* Bc = (const float*)d_in[3];
    const float* D  = (const float*)d_in[4];
    float* out = (float*)d_out;
    vqc_kernel<<<512, NT, 0, stream>>>(X, TH, A, Bc, D, out);
}

// Round 15
// 45.418 us; speedup vs baseline: 1.1948x; 1.1948x over previous
//
#include <hip/hip_runtime.h>
#include <math.h>

#define NQ 14
#define NSTATE (1 << 14)
#define DEPTH  6
#define NT     1024             // 16 waves/block

typedef float v2f __attribute__((ext_vector_type(2)));

// dword-index swizzle: XOR bits 6,7,8 into 2,3,4 (GF(2)-linear)
__device__ __forceinline__ int swz(int n) { return n ^ ((n >> 4) & 28); }

// fused CNOT ladders (even after odd): m = sigma_e(sigma_o(n))
__device__ __forceinline__ int sigma(int n) {
    int m = n ^ ((n & 0x1554) >> 1);
    return m ^ ((m & 0x2AAA) >> 1);
}

// ---- VOP3P packed helpers (correctness-proven in r11); cs = (c, s) ----
__device__ __forceinline__ v2f pkmul_cc(v2f a, v2f cs) {   // d = a * c
    v2f d;
    asm("v_pk_mul_f32 %0, %1, %2 op_sel:[0,0] op_sel_hi:[1,0]"
        : "=v"(d) : "v"(a), "v"(cs));
    return d;
}
__device__ __forceinline__ v2f pkmul_ss(v2f a, v2f cs) {   // d = a * s
    v2f d;
    asm("v_pk_mul_f32 %0, %1, %2 op_sel:[0,1] op_sel_hi:[1,1]"
        : "=v"(d) : "v"(a), "v"(cs));
    return d;
}
__device__ __forceinline__ v2f pkfma_cc(v2f a, v2f cs, v2f acc) {  // a*c + acc
    v2f d;
    asm("v_pk_fma_f32 %0, %1, %2, %3 op_sel:[0,0,0] op_sel_hi:[1,0,1]"
        : "=v"(d) : "v"(a), "v"(cs), "v"(acc));
    return d;
}
__device__ __forceinline__ v2f pkfma_nss(v2f a, v2f cs, v2f acc) { // -(a*s) + acc
    v2f d;
    asm("v_pk_fma_f32 %0, %1, %2, %3 op_sel:[0,1,0] op_sel_hi:[1,1,1] neg_lo:[0,1,0] neg_hi:[0,1,0]"
        : "=v"(d) : "v"(a), "v"(cs), "v"(acc));
    return d;
}
__device__ __forceinline__ v2f pkfma_sw(v2f a, v2f cs, v2f acc) {
    // d.lo = -s*a.hi + acc.lo ; d.hi = s*a.lo + acc.hi
    v2f d;
    asm("v_pk_fma_f32 %0, %1, %2, %3 op_sel:[1,1,0] op_sel_hi:[0,1,1] neg_lo:[0,1,0] neg_hi:[0,0,0]"
        : "=v"(d) : "v"(a), "v"(cs), "v"(acc));
    return d;
}

// wire on p-index bit 0 (intra register pair): 2 pk-instr per v2f
__device__ __forceinline__ void ry_pk0(float (&p)[16], v2f cs) {
#pragma unroll
    for (int j = 0; j < 8; ++j) {
        v2f v = *(v2f*)&p[2 * j];
        *(v2f*)&p[2 * j] = pkfma_sw(v, cs, pkmul_cc(v, cs));
    }
}
// wire on p-index bit JB (1..3): 4 pk-instr per v2f pair
template <int JB>
__device__ __forceinline__ void ry_pkN(float (&p)[16], v2f cs) {
#pragma unroll
    for (int j = 0; j < 8; ++j) {
        if (!((j >> (JB - 1)) & 1)) {
            const int j1 = j | (1 << (JB - 1));
            v2f a0 = *(v2f*)&p[2 * j], a1 = *(v2f*)&p[2 * j1];
            *(v2f*)&p[2 * j]  = pkfma_nss(a1, cs, pkmul_cc(a0, cs));
            *(v2f*)&p[2 * j1] = pkfma_cc(a1, cs, pkmul_ss(a0, cs));
        }
    }
}
// all four wires of a pass; q0 acts on bit0, q1..q3 on bits 1..3
__device__ __forceinline__ void ry4_pk(float (&p)[16], float2 q0, float2 q1,
                                       float2 q2, float2 q3) {
    v2f c0, c1, c2, c3;
    c0.x = q0.x; c0.y = q0.y;
    c1.x = q1.x; c1.y = q1.y;
    c2.x = q2.x; c2.y = q2.y;
    c3.x = q3.x; c3.y = q3.y;
    ry_pk0(p, c0);
    ry_pkN<1>(p, c1);
    ry_pkN<2>(p, c2);
    ry_pkN<3>(p, c3);
}

// RY across lane bit 0/1 via DPP quad_perm (VALU pipe, verified r9/r10).
template <int CTRL>
__device__ __forceinline__ void ry_dpp(float (&p)[16], float c, float sg) {
#pragma unroll
    for (int i = 0; i < 16; ++i) {
        float partner = __int_as_float(__builtin_amdgcn_update_dpp(
            0, __float_as_int(p[i]), CTRL, 0xF, 0xF, true));
        p[i] = c * p[i] + sg * partner;
    }
}

__global__ __launch_bounds__(NT, 4)
void vqc_kernel(const float* __restrict__ X,    // (512,14)
                const float* __restrict__ TH,   // (6,14)
                const float* __restrict__ A,    // (14,28)
                const float* __restrict__ Bc,   // (14,28)  unused: state stays real
                const float* __restrict__ D,    // (14,8)
                float* __restrict__ out)        // (512,2)
{
    __shared__ __align__(16) float st[NSTATE];  // 64 KiB real state
    __shared__ float2 tb[DEPTH * NQ];           // (cos,sin) per theta
    __shared__ float2 xf[NQ];                   // (c-s, c+s) per amplitude bit j
    __shared__ float  red[2 * (NT / 64)];

    const int t = threadIdx.x;
    const int b = blockIdx.x;

    // ---- trig tables (uniform work once per block) ----
    if (t < DEPTH * NQ) {
        float s, c;
        __sincosf(0.5f * TH[t], &s, &c);
        tb[t] = make_float2(c, s);
    } else if (t < DEPTH * NQ + NQ) {
        const int j = t - DEPTH * NQ;           // amplitude-bit j <-> wire 13-j
        float s, c;
        __sincosf(0.5f * X[b * NQ + (13 - j)], &s, &c);
        xf[j] = make_float2(c - s, c + s);
    }
    __syncthreads();

    // ---- layer 0 P1: product state at sigma(n), rotate wires 13..10 (amp 0-3) ----
    {
        const int mt = sigma(t << 4);
        float sh = 1.0f / 128.0f;
#pragma unroll
        for (int j = 4; j < 14; ++j) {
            float2 f = xf[j];
            sh *= ((mt >> j) & 1) ? f.y : f.x;
        }
        float fa[4], fb[4];
#pragma unroll
        for (int j = 0; j < 4; ++j) {
            float2 f = xf[j];
            const int mj = (mt >> j) & 1;
            fa[j] = mj ? f.y : f.x;
            fb[j] = mj ? f.x : f.y;
        }
        float p[16];
#pragma unroll
        for (int i = 0; i < 16; ++i) {
            const int sl = sigma(i);
            float v = sh;
            v *= (sl & 1)        ? fb[0] : fa[0];
            v *= ((sl >> 1) & 1) ? fb[1] : fa[1];
            v *= ((sl >> 2) & 1) ? fb[2] : fa[2];
            v *= ((sl >> 3) & 1) ? fb[3] : fa[3];
            p[i] = v;
        }
        ry4_pk(p, tb[13], tb[12], tb[11], tb[10]);
        const int wb = swz(t << 4);
#pragma unroll
        for (int g = 0; g < 4; ++g)
            *(float4*)&st[wb ^ (g << 2)] =
                make_float4(p[4 * g], p[4 * g + 1], p[4 * g + 2], p[4 * g + 3]);
    }
    __syncthreads();

    // ---- layers: P1 (CNOT + 13-10), P2 (9-6 reg + 5,4 DPP), P3 (3-0) ----
    for (int k = 0; k < DEPTH; ++k) {
        const float2* tbk = tb + k * NQ;

        if (k > 0) {
            // P1: gather through sigma (b128). Lane-dependent XOR 12 folded
            // into the read address; remaining permute = compile-time renaming.
            const int rb = swz(sigma(t << 4) & ~15) ^ ((t & 1) * 12);
            float tmpf[16];
#pragma unroll
            for (int g = 0; g < 4; ++g)
                *(float4*)&tmpf[g * 4] = *(const float4*)&st[rb ^ (g << 2)];
            float p[16];
#pragma unroll
            for (int i = 0; i < 16; ++i) {
                const int i0 = i & 1, i1 = (i >> 1) & 1, i2 = (i >> 2) & 1, i3 = (i >> 3) & 1;
                const int s = (i0 ^ i1 ^ i2) | ((i1 ^ i2) << 1) | ((i2 ^ i3) << 2) | (i3 << 3);
                p[i] = tmpf[s];                  // compile-time shuffle
            }
            __syncthreads();                     // all gather-reads before any write
            ry4_pk(p, tbk[13], tbk[12], tbk[11], tbk[10]);
            const int wb = swz(t << 4);
#pragma unroll
            for (int g = 0; g < 4; ++g)
                *(float4*)&st[wb ^ (g << 2)] =
                    make_float4(p[4 * g], p[4 * g + 1], p[4 * g + 2], p[4 * g + 3]);
            __syncthreads();
        }

        // P2: in-place RMW. regs = amp 4-7 (wires 9-6); DPP lanes t0,t1 = amp 8,9
        // (wires 5,4). Pairs over amp bit 5 -> additive +32 dwords (ds_read2).
        {
            const int raw = ((t >> 2) & 15) | ((t & 1) << 8) | ((t & 2) << 8)
                          | (((t >> 6) & 15) << 10);
            const int base2 = swz(raw);
            float p[16];
#pragma unroll
            for (int ip = 0; ip < 16; ++ip) {
                if ((ip & 2) == 0) {
                    const int v = base2 ^ (ip << 4) ^ (ip & 12);   // swz(ip<<4) folded
                    p[ip]     = st[v];
                    p[ip | 2] = st[v + 32];
                }
            }
            // p bit0 = amp4 (wire 9), bit1 = amp5 (wire 8), bits2,3 = amp6,7
            ry4_pk(p, tbk[9], tbk[8], tbk[7], tbk[6]);
            float2 w5 = tbk[5], w4 = tbk[4];
            const float sg5 = (t & 1) ? w5.y : -w5.y;   // amp8 = lane bit 0
            const float sg4 = (t & 2) ? w4.y : -w4.y;   // amp9 = lane bit 1
            ry_dpp<0xB1>(p, w5.x, sg5);
            ry_dpp<0x4E>(p, w4.x, sg4);
#pragma unroll
            for (int ip = 0; ip < 16; ++ip) {
                if ((ip & 2) == 0) {
                    const int v = base2 ^ (ip << 4) ^ (ip & 12);
                    st[v]      = p[ip];
                    st[v + 32] = p[ip | 2];
                }
            }
            __syncthreads();
        }

        // P3: in-place RMW. regs = amp 10-13 (wires 3-0). Addresses purely
        // additive: base + i*1024 dwords -> read2st64 / imm offsets.
        {
            const int base3 = swz(t);
            float p[16];
#pragma unroll
            for (int i = 0; i < 16; ++i) p[i] = st[base3 + (i << 10)];
            ry4_pk(p, tbk[3], tbk[2], tbk[1], tbk[0]);
#pragma unroll
            for (int i = 0; i < 16; ++i) st[base3 + (i << 10)] = p[i];
            __syncthreads();
        }
    }

    // ---- expectations (real state: B drops out) ----
    float e[2];
#pragma unroll
    for (int q = 0; q < 2; ++q) {
        const int shift = 11 - q;
        float dg[8];
#pragma unroll
        for (int i = 0; i < 7; ++i) dg[i] = 2.0f * D[q * 8 + i + 1];
        dg[7] = 0.0f;
        float acc = 0.0f;
        const int lowmask = (1 << shift) - 1;
        for (int r = t; r < NSTATE / 8; r += NT) {   // 2 iterations
            const int base = ((r >> shift) << (shift + 3)) | (r & lowmask);
            float ps[8];
#pragma unroll
            for (int i = 0; i < 8; ++i) ps[i] = st[swz(base + (i << shift))];
#pragma unroll
            for (int i = 0; i < 8; ++i) acc += dg[i] * ps[i] * ps[i];
            int kk = 0;
#pragma unroll
            for (int i = 1; i < 8; ++i)
#pragma unroll
                for (int j = 0; j < i; ++j, ++kk)
                    acc += 2.0f * A[q * 28 + kk] * ps[i] * ps[j];
        }
        e[q] = acc;
    }

    // ---- block reduction ----
    float v0 = e[0], v1 = e[1];
#pragma unroll
    for (int o = 32; o > 0; o >>= 1) {
        v0 += __shfl_down(v0, o);
        v1 += __shfl_down(v1, o);
    }
    if ((t & 63) == 0) {
        red[(t >> 6) * 2]     = v0;
        red[(t >> 6) * 2 + 1] = v1;
    }
    __syncthreads();
    if (t == 0) {
        float s0 = 0.0f, s1 = 0.0f;
#pragma unroll
        for (int i = 0; i < NT / 64; ++i) { s0 += red[i * 2]; s1 += red[i * 2 + 1]; }
        out[b * 2 + 0] = s0;
        out[b * 2 + 1] = s1;
    }
}

extern "C" void kernel_launch(void* const* d_in, const int* in_sizes, int n_in,
                              void* d_out, int out_size, void* d_ws, size_t ws_size,
                              hipStream_t stream) {
    const float* X  = (const float*)d_in[0];
    const float* TH = (const float*)d_in[1];
    const float* A  = (const float*)d_in[2];
    const float* Bc = (const float*)d_in[3];
    const float* D  = (const float*)d_in[4];
    float* out = (float*)d_out;
    vqc_kernel<<<512, NT, 0, stream>>>(X, TH, A, Bc, D, out);
}